// Round 19
// baseline (127.280 us; speedup 1.0000x reference)
//
#include <hip/hip_runtime.h>
#include <hip/hip_bf16.h>

typedef unsigned short ushort_t;
typedef __attribute__((ext_vector_type(4))) short short4v;
typedef __attribute__((ext_vector_type(8))) short short8;
typedef __attribute__((ext_vector_type(4))) float f32x4;
typedef __attribute__((ext_vector_type(16))) float f32x16;
typedef __attribute__((ext_vector_type(2))) unsigned int uint2v;

#define EMBED 1024
#define NHEAD 16
#define HDIM 64
#define BB 2
#define SSEQ 2048
#define MROWS (BB*SSEQ)          // 4096
#define QKV_N (3*EMBED)          // 3072
#define PER_BUF (MROWS*EMBED)    // 4194304 elems = 8MB bf16

__device__ __forceinline__ ushort_t f2bf(float f) {
    union { float f; unsigned int u; } x; x.f = f;
    unsigned int r = x.u + 0x7fffu + ((x.u >> 16) & 1u);
    return (ushort_t)(r >> 16);
}
// HW packed f32x2 -> bf16x2 (RNE), single VALU op
__device__ __forceinline__ unsigned cvt_pk_bf16(float lo, float hi) {
    unsigned r;
    asm("v_cvt_pk_bf16_f32 %0, %1, %2" : "=v"(r) : "v"(lo), "v"(hi));
    return r;
}

__device__ __forceinline__ void gload16(const void* g, void* l) {
    __builtin_amdgcn_global_load_lds(
        (const __attribute__((address_space(1))) unsigned int*)g,
        (__attribute__((address_space(3))) unsigned int*)l, 16, 0, 0);
}

// ---------------- cast x (fp32 -> bf16), vectorized ----------------
__global__ void cast_bf16_kernel(const float* __restrict__ in, ushort_t* __restrict__ out, int n) {
    int i = (blockIdx.x * blockDim.x + threadIdx.x) * 4;
    if (i + 3 < n) {
        float4 v = *(const float4*)(in + i);
        out[i+0] = f2bf(v.x); out[i+1] = f2bf(v.y);
        out[i+2] = f2bf(v.z); out[i+3] = f2bf(v.w);
    }
}

// ---------------- 4x W [K,N] fp32 -> Wt [N,K] bf16, one launch ----------------
__global__ void transpose_cast4_kernel(
    const float* __restrict__ W0, const float* __restrict__ W1,
    const float* __restrict__ W2, const float* __restrict__ W3,
    ushort_t* __restrict__ T0, ushort_t* __restrict__ T1,
    ushort_t* __restrict__ T2, ushort_t* __restrict__ T3)
{
    __shared__ float tile[32][33];
    int z = blockIdx.z;
    const float* W = (z == 0) ? W0 : (z == 1) ? W1 : (z == 2) ? W2 : W3;
    ushort_t* Wt   = (z == 0) ? T0 : (z == 1) ? T1 : (z == 2) ? T2 : T3;
    int tx = threadIdx.x, ty = threadIdx.y;   // 32 x 8
    int n0 = blockIdx.x * 32, k0 = blockIdx.y * 32;
    #pragma unroll
    for (int i = 0; i < 4; i++)
        tile[ty*4+i][tx] = W[(size_t)(k0 + ty*4 + i) * EMBED + n0 + tx];
    __syncthreads();
    #pragma unroll
    for (int i = 0; i < 4; i++)
        Wt[(size_t)(n0 + ty*4 + i) * EMBED + k0 + tx] = f2bf(tile[tx][ty*4+i]);
}

// ---------------- QKV GEMM: 256x256 tile, 8 waves, counted-vmcnt pipeline ----------------
// A [4096,1024] bf16, Bt [3072,1024] bf16.
// q/k -> [B,H,S,Dh] (q pre-scaled by 0.125*log2e); V -> vt_out [B,H,D,S] directly.
__global__ __launch_bounds__(512, 1) void gemm_qkv_256_kernel(
    const ushort_t* __restrict__ A,
    const ushort_t* __restrict__ Bt,
    const float* __restrict__ b0, const float* __restrict__ b1, const float* __restrict__ b2,
    ushort_t* __restrict__ qk_out,
    ushort_t* __restrict__ vt_out)
{
    __shared__ __attribute__((aligned(16))) ushort_t Am[2][256*64];
    __shared__ __attribute__((aligned(16))) ushort_t Bm[2][256*64];
    const int K = 1024, NT = 16;

    int t = threadIdx.x, w = t >> 6, l = t & 63;   // 8 waves: wr in {0,1}, wc in {0..3}
    int wr = w >> 2, wc = w & 3;
    int lrow = l & 15, lhi = l >> 4;
    int lr = l >> 3;
    int colel = 8 * ((l & 7) ^ lr);               // pre-swizzled global col (elems)

    // XCD-chunked bijective swizzle (nwg = 12*16 = 192, %8 == 0)
    int gx = gridDim.x;
    int flat = blockIdx.y * gx + blockIdx.x;
    int q8 = (gx * gridDim.y) >> 3;
    int nf = (flat & 7) * q8 + (flat >> 3);
    int m0 = (nf / gx) * 256, n0 = (nf % gx) * 256;

    f32x4 acc[8][4];
    #pragma unroll
    for (int mi = 0; mi < 8; mi++)
        #pragma unroll
        for (int ni = 0; ni < 4; ni++)
            #pragma unroll
            for (int c = 0; c < 4; c++) acc[mi][ni][c] = 0.f;

    // 8 gload16/thread per tile: each wave stages rows [w*32, w*32+32) of A and B
    #define STAGE256(buf, k0v) { \
        _Pragma("unroll") \
        for (int p = 0; p < 4; p++) { \
            int row = w*32 + p*8 + lr; \
            gload16(&A [(size_t)(m0 + row)*K + (k0v) + colel], &Am[buf][(w*32 + p*8)*64]); \
            gload16(&Bt[(size_t)(n0 + row)*K + (k0v) + colel], &Bm[buf][(w*32 + p*8)*64]); \
        } }

    STAGE256(0, 0)
    STAGE256(1, 64)
    asm volatile("s_waitcnt vmcnt(8)" ::: "memory");   // tile 0 landed; tile 1 in flight
    __builtin_amdgcn_sched_barrier(0);
    asm volatile("s_barrier" ::: "memory");

    for (int kt = 0; kt < NT; kt++) {
        int cur = kt & 1;
        const ushort_t* As = Am[cur];
        const ushort_t* Bs = Bm[cur];

        // B fragments for the whole tile (held across quadrants)
        short8 bf[4][2];
        #pragma unroll
        for (int ni = 0; ni < 4; ni++)
            #pragma unroll
            for (int kk = 0; kk < 2; kk++) {
                int r = wc*64 + ni*16 + lrow;
                bf[ni][kk] = *(const short8*)&Bs[r*64 + ((kk*32 + lhi*8) ^ ((r & 7) << 3))];
            }

        // 4 quadrants x 16 MFMA
        #pragma unroll
        for (int qd = 0; qd < 4; qd++) {
            short8 af[2][2];
            #pragma unroll
            for (int m2 = 0; m2 < 2; m2++)
                #pragma unroll
                for (int kk = 0; kk < 2; kk++) {
                    int r = wr*128 + (qd*2 + m2)*16 + lrow;
                    af[m2][kk] = *(const short8*)&As[r*64 + ((kk*32 + lhi*8) ^ ((r & 7) << 3))];
                }
            __builtin_amdgcn_s_setprio(1);
            #pragma unroll
            for (int m2 = 0; m2 < 2; m2++)
                #pragma unroll
                for (int ni = 0; ni < 4; ni++)
                    #pragma unroll
                    for (int kk = 0; kk < 2; kk++)
                        acc[qd*2 + m2][ni] = __builtin_amdgcn_mfma_f32_16x16x32_bf16(
                            af[m2][kk], bf[ni][kk], acc[qd*2 + m2][ni], 0, 0, 0);
            __builtin_amdgcn_s_setprio(0);
        }

        // all waves done reading buf[cur] -> safe to overwrite with tile kt+2
        __builtin_amdgcn_sched_barrier(0);
        asm volatile("s_barrier" ::: "memory");
        if (kt + 2 < NT) {
            STAGE256(cur, (kt + 2) * 64)
            asm volatile("s_waitcnt vmcnt(8)" ::: "memory");   // tile kt+1 landed; kt+2 in flight
        } else if (kt + 1 < NT) {
            asm volatile("s_waitcnt vmcnt(0)" ::: "memory");   // tail: last tile landed
        }
        __builtin_amdgcn_sched_barrier(0);
        asm volatile("s_barrier" ::: "memory");
    }
    #undef STAGE256

    // epilogue: scatter q/k (fragment [B,H,S,D]) and V transposed [B,H,D,S]
    #pragma unroll
    for (int mi = 0; mi < 8; mi++)
        #pragma unroll
        for (int ni = 0; ni < 4; ni++) {
            int col = n0 + wc*64 + ni*16 + lrow;
            int which = col >> 10, hc = col & 1023;
            int h = hc >> 6, d = hc & 63;
            if (which == 2) {
                int row0 = m0 + wr*128 + mi*16 + lhi*4;
                int b = row0 >> 11, s0 = row0 & 2047;
                int bh = b*NHEAD + h;
                short4v pk;
                #pragma unroll
                for (int c = 0; c < 4; c++)
                    pk[c] = (short)f2bf(acc[mi][ni][c] + b2[hc]);
                *(short4v*)&vt_out[((size_t)bh*HDIM + d)*SSEQ + s0] = pk;
            } else {
                const float* bp = (which == 0) ? b0 : b1;
                #pragma unroll
                for (int c = 0; c < 4; c++) {
                    int row = m0 + wr*128 + mi*16 + lhi*4 + c;
                    float v = acc[mi][ni][c] + bp[hc];
                    if (which == 0) v *= 0.18033688011112042f;  // 0.125 * log2(e)
                    int b = row >> 11, s = row & 2047;
                    qk_out[(size_t)which*PER_BUF + ((size_t)((b*NHEAD + h)*SSEQ) + s)*HDIM + d] = f2bf(v);
                }
            }
        }
}

// ---------------- GEMM 128^2 (proven r13, BK=64) — out-projection only ----------------
__global__ __launch_bounds__(256) void gemm_out_kernel(
    const ushort_t* __restrict__ A,   // [M,K] bf16
    const ushort_t* __restrict__ Bt,  // [N,K] bf16
    const float* __restrict__ b0,
    float* __restrict__ Cout,
    int M, int N, int K)
{
    __shared__ __attribute__((aligned(16))) ushort_t Asm[128*64];
    __shared__ __attribute__((aligned(16))) ushort_t Bsm[128*64];
    int t = threadIdx.x;
    int w = t >> 6, l = t & 63;
    int wr = w >> 1, wc = w & 1;
    int lrow = l & 15, lhi = l >> 4;

    int gx = gridDim.x;
    int flat = blockIdx.y * gx + blockIdx.x;
    int q8 = (gx * gridDim.y) >> 3;
    int nf = (flat & 7) * q8 + (flat >> 3);
    int m0 = (nf / gx) * 128, n0 = (nf % gx) * 128;

    int srow8 = l >> 3;
    int colel = 8 * ((l & 7) ^ srow8);

    f32x4 acc[4][4];
    #pragma unroll
    for (int mi = 0; mi < 4; mi++)
        #pragma unroll
        for (int ni = 0; ni < 4; ni++)
            #pragma unroll
            for (int c = 0; c < 4; c++) acc[mi][ni][c] = 0.f;

    for (int k0 = 0; k0 < K; k0 += 64) {
        __syncthreads();
        #pragma unroll
        for (int p = 0; p < 4; p++) {
            int row = w*32 + p*8 + srow8;
            gload16(&A [(size_t)(m0 + row)*K + k0 + colel], &Asm[(w*32 + p*8)*64]);
            gload16(&Bt[(size_t)(n0 + row)*K + k0 + colel], &Bsm[(w*32 + p*8)*64]);
        }
        __syncthreads();
        #pragma unroll
        for (int kk = 0; kk < 2; kk++) {
            short8 af[4], bfr[4];
            #pragma unroll
            for (int mi = 0; mi < 4; mi++) {
                int r = wr*64 + mi*16 + lrow;
                af[mi] = *(short8*)&Asm[r*64 + ((kk*32 + lhi*8) ^ ((r & 7) << 3))];
            }
            #pragma unroll
            for (int ni = 0; ni < 4; ni++) {
                int r = wc*64 + ni*16 + lrow;
                bfr[ni] = *(short8*)&Bsm[r*64 + ((kk*32 + lhi*8) ^ ((r & 7) << 3))];
            }
            __builtin_amdgcn_s_setprio(1);
            #pragma unroll
            for (int mi = 0; mi < 4; mi++)
                #pragma unroll
                for (int ni = 0; ni < 4; ni++)
                    acc[mi][ni] = __builtin_amdgcn_mfma_f32_16x16x32_bf16(af[mi], bfr[ni], acc[mi][ni], 0, 0, 0);
            __builtin_amdgcn_s_setprio(0);
        }
    }

    #pragma unroll
    for (int mi = 0; mi < 4; mi++)
        #pragma unroll
        for (int ni = 0; ni < 4; ni++) {
            int col = n0 + wc*64 + ni*16 + lrow;
            #pragma unroll
            for (int c = 0; c < 4; c++) {
                int row = m0 + wr*64 + mi*16 + lhi*4 + c;
                Cout[(size_t)row * N + col] = acc[mi][ni][c] + b0[col];
            }
        }
}

// ---------------- flash attention v2e (proven r18): 8-wave blocks, QBLK=256, KVBLK=128 ----------------
#define MFMA32(a,b,c) __builtin_amdgcn_mfma_f32_32x32x16_bf16(a, b, c, 0, 0, 0)

__global__ __launch_bounds__(512, 1) void flash_attn2_kernel(
    const ushort_t* __restrict__ q,
    const ushort_t* __restrict__ k,
    const ushort_t* __restrict__ vt,
    ushort_t* __restrict__ o)
{
    __shared__ __attribute__((aligned(16))) ushort_t Ks[2][2][64*64];
    __shared__ __attribute__((aligned(16))) ushort_t Vs[2][2][64*64];

    int t = threadIdx.x, w = t >> 6, l = t & 63;
    int l31 = l & 31, hi = l >> 5;

    int flat = blockIdx.x;
    int wg = (flat & 7) * 32 + (flat >> 3);
    int bh = wg >> 3;
    int q0 = (wg & 7) * 256;

    const ushort_t* qp = q  + (size_t)bh * SSEQ * HDIM;
    const ushort_t* kp = k  + (size_t)bh * SSEQ * HDIM;
    const ushort_t* vp = vt + (size_t)bh * HDIM * SSEQ;

    int lr = l >> 3, lc = l & 7;
    int colel = 8 * (lc ^ lr);

    short8 qf[4];
    int qrow = q0 + w*32 + l31;
    #pragma unroll
    for (int st = 0; st < 4; st++)
        qf[st] = *(const short8*)&qp[(size_t)qrow*HDIM + st*16 + hi*8];

    f32x16 o0 = {}, o1 = {};
    float m_run = -1e30f, l_run = 0.f;

    #define STAGE(buf, kv0) { \
        _Pragma("unroll") \
        for (int sub = 0; sub < 2; sub++) { \
            int row = w*8 + lr; \
            gload16(&kp[(size_t)(kv0 + sub*64 + row)*HDIM + colel], &Ks[buf][sub][(w*8)*64]); \
            gload16(&vp[(size_t)row*SSEQ + (kv0) + sub*64 + colel], &Vs[buf][sub][(w*8)*64]); \
        } }

    STAGE(0, 0)
    asm volatile("s_waitcnt vmcnt(0)");
    __syncthreads();
    int cur = 0;

    for (int kv0 = 0; kv0 < SSEQ; kv0 += 128) {
        if (kv0 + 128 < SSEQ) { STAGE(cur ^ 1, kv0 + 128) }

        f32x16 s0 = {}, s1 = {}, s2 = {}, s3 = {};
        __builtin_amdgcn_s_setprio(1);
        #pragma unroll
        for (int st = 0; st < 4; st++) {
            int colb = st*16 + hi*8;
            int sw0 = colb ^ ((l31 & 7) << 3);
            short8 kf0 = *(const short8*)&Ks[cur][0][l31*64        + sw0];
            short8 kf1 = *(const short8*)&Ks[cur][0][(32 + l31)*64 + sw0];
            short8 kf2 = *(const short8*)&Ks[cur][1][l31*64        + sw0];
            short8 kf3 = *(const short8*)&Ks[cur][1][(32 + l31)*64 + sw0];
            s0 = MFMA32(kf0, qf[st], s0);
            s1 = MFMA32(kf1, qf[st], s1);
            s2 = MFMA32(kf2, qf[st], s2);
            s3 = MFMA32(kf3, qf[st], s3);
        }
        __builtin_amdgcn_s_setprio(0);

        float ma = fmaxf(s0[0], s0[1]);
        float mb = fmaxf(s0[2], s0[3]);
        float mc = fmaxf(s0[4], s0[5]);
        float md = fmaxf(s0[6], s0[7]);
        ma = fmaxf(fmaxf(ma, s0[8]),  s0[9]);
        mb = fmaxf(fmaxf(mb, s0[10]), s0[11]);
        mc = fmaxf(fmaxf(mc, s0[12]), s0[13]);
        md = fmaxf(fmaxf(md, s0[14]), s0[15]);
        ma = fmaxf(fmaxf(ma, s1[0]),  s1[1]);
        mb = fmaxf(fmaxf(mb, s1[2]),  s1[3]);
        mc = fmaxf(fmaxf(mc, s1[4]),  s1[5]);
        md = fmaxf(fmaxf(md, s1[6]),  s1[7]);
        ma = fmaxf(fmaxf(ma, s1[8]),  s1[9]);
        mb = fmaxf(fmaxf(mb, s1[10]), s1[11]);
        mc = fmaxf(fmaxf(mc, s1[12]), s1[13]);
        md = fmaxf(fmaxf(md, s1[14]), s1[15]);
        ma = fmaxf(fmaxf(ma, s2[0]),  s2[1]);
        mb = fmaxf(fmaxf(mb, s2[2]),  s2[3]);
        mc = fmaxf(fmaxf(mc, s2[4]),  s2[5]);
        md = fmaxf(fmaxf(md, s2[6]),  s2[7]);
        ma = fmaxf(fmaxf(ma, s2[8]),  s2[9]);
        mb = fmaxf(fmaxf(mb, s2[10]), s2[11]);
        mc = fmaxf(fmaxf(mc, s2[12]), s2[13]);
        md = fmaxf(fmaxf(md, s2[14]), s2[15]);
        ma = fmaxf(fmaxf(ma, s3[0]),  s3[1]);
        mb = fmaxf(fmaxf(mb, s3[2]),  s3[3]);
        mc = fmaxf(fmaxf(mc, s3[4]),  s3[5]);
        md = fmaxf(fmaxf(md, s3[6]),  s3[7]);
        ma = fmaxf(fmaxf(ma, s3[8]),  s3[9]);
        mb = fmaxf(fmaxf(mb, s3[10]), s3[11]);
        mc = fmaxf(fmaxf(mc, s3[12]), s3[13]);
        md = fmaxf(fmaxf(md, s3[14]), s3[15]);
        float mx = fmaxf(fmaxf(ma, mb), fmaxf(mc, md));
        mx = fmaxf(mx, __shfl_xor(mx, 32));

        if (__any(mx > m_run + 8.f)) {       // defer-max (T13)
            float mnew = fmaxf(m_run, mx);
            float alpha = __builtin_amdgcn_exp2f(m_run - mnew);
            #pragma unroll
            for (int r = 0; r < 16; r++) { o0[r] *= alpha; o1[r] *= alpha; }
            l_run *= alpha;
            m_run = mnew;
        }
        float r0 = 0.f, r1 = 0.f, r2 = 0.f, r3 = 0.f;
        #pragma unroll
        for (int r = 0; r < 16; r += 4) {
            s0[r]   = __builtin_amdgcn_exp2f(s0[r]   - m_run); r0 += s0[r];
            s0[r+1] = __builtin_amdgcn_exp2f(s0[r+1] - m_run); r1 += s0[r+1];
            s0[r+2] = __builtin_amdgcn_exp2f(s0[r+2] - m_run); r2 += s0[r+2];
            s0[r+3] = __builtin_amdgcn_exp2f(s0[r+3] - m_run); r3 += s0[r+3];
        }
        #pragma unroll
        for (int r = 0; r < 16; r += 4) {
            s1[r]   = __builtin_amdgcn_exp2f(s1[r]   - m_run); r0 += s1[r];
            s1[r+1] = __builtin_amdgcn_exp2f(s1[r+1] - m_run); r1 += s1[r+1];
            s1[r+2] = __builtin_amdgcn_exp2f(s1[r+2] - m_run); r2 += s1[r+2];
            s1[r+3] = __builtin_amdgcn_exp2f(s1[r+3] - m_run); r3 += s1[r+3];
        }
        #pragma unroll
        for (int r = 0; r < 16; r += 4) {
            s2[r]   = __builtin_amdgcn_exp2f(s2[r]   - m_run); r0 += s2[r];
            s2[r+1] = __builtin_amdgcn_exp2f(s2[r+1] - m_run); r1 += s2[r+1];
            s2[r+2] = __builtin_amdgcn_exp2f(s2[r+2] - m_run); r2 += s2[r+2];
            s2[r+3] = __builtin_amdgcn_exp2f(s2[r+3] - m_run); r3 += s2[r+3];
        }
        #pragma unroll
        for (int r = 0; r < 16; r += 4) {
            s3[r]   = __builtin_amdgcn_exp2f(s3[r]   - m_run); r0 += s3[r];
            s3[r+1] = __builtin_amdgcn_exp2f(s3[r+1] - m_run); r1 += s3[r+1];
            s3[r+2] = __builtin_amdgcn_exp2f(s3[r+2] - m_run); r2 += s3[r+2];
            s3[r+3] = __builtin_amdgcn_exp2f(s3[r+3] - m_run); r3 += s3[r+3];
        }
        float rs = (r0 + r1) + (r2 + r3);
        rs += __shfl_xor(rs, 32);
        l_run += rs;

        short8 pfr[8];
        #define PACK8(SV, KS0) { \
            unsigned a0 = cvt_pk_bf16(SV[0], SV[1]); \
            unsigned a1 = cvt_pk_bf16(SV[2], SV[3]); \
            unsigned b0 = cvt_pk_bf16(SV[4], SV[5]); \
            unsigned b1 = cvt_pk_bf16(SV[6], SV[7]); \
            uint2v rr0 = __builtin_amdgcn_permlane32_swap(a0, b0, false, false); \
            uint2v rr1 = __builtin_amdgcn_permlane32_swap(a1, b1, false, false); \
            union { unsigned u[4]; short8 v; } pfa; \
            pfa.u[0] = rr0.x; pfa.u[1] = rr1.x; pfa.u[2] = rr0.y; pfa.u[3] = rr1.y; \
            pfr[KS0] = pfa.v; \
            unsigned c0 = cvt_pk_bf16(SV[8], SV[9]); \
            unsigned c1 = cvt_pk_bf16(SV[10], SV[11]); \
            unsigned d0 = cvt_pk_bf16(SV[12], SV[13]); \
            unsigned d1 = cvt_pk_bf16(SV[14], SV[15]); \
            uint2v rr2 = __builtin_amdgcn_permlane32_swap(c0, d0, false, false); \
            uint2v rr3 = __builtin_amdgcn_permlane32_swap(c1, d1, false, false); \
            union { unsigned u[4]; short8 v; } pfb; \
            pfb.u[0] = rr2.x; pfb.u[1] = rr3.x; pfb.u[2] = rr2.y; pfb.u[3] = rr3.y; \
            pfr[(KS0)+1] = pfb.v; \
        }
        PACK8(s0, 0)
        PACK8(s1, 2)
        PACK8(s2, 4)
        PACK8(s3, 6)
        #undef PACK8

        __builtin_amdgcn_s_setprio(1);
        #pragma unroll
        for (int ks = 0; ks < 8; ks++) {
            int sub = ks >> 2;
            int colb = (ks & 3)*16 + hi*8;
            int sw = colb ^ ((l31 & 7) << 3);
            short8 vf0 = *(const short8*)&Vs[cur][sub][l31*64        + sw];
            short8 vf1 = *(const short8*)&Vs[cur][sub][(32 + l31)*64 + sw];
            o0 = MFMA32(vf0, pfr[ks], o0);
            o1 = MFMA32(vf1, pfr[ks], o1);
        }
        __builtin_amdgcn_s_setprio(0);

        asm volatile("s_waitcnt vmcnt(0)");
        __syncthreads();
        cur ^= 1;
    }

    float rl = 1.f / l_run;
    ushort_t* Ot = ((ushort_t*)Ks) + w*(32*64);
    #pragma unroll
    for (int dt = 0; dt < 2; dt++)
        #pragma unroll
        for (int rq = 0; rq < 4; rq++) {
            float v0 = (dt ? o1[rq*4+0] : o0[rq*4+0]) * rl;
            float v1 = (dt ? o1[rq*4+1] : o0[rq*4+1]) * rl;
            float v2 = (dt ? o1[rq*4+2] : o0[rq*4+2]) * rl;
            float v3 = (dt ? o1[rq*4+3] : o0[rq*4+3]) * rl;
            int d0 = dt*32 + rq*8 + hi*4;
            uint2v pw = { cvt_pk_bf16(v0, v1), cvt_pk_bf16(v2, v3) };
            *(uint2v*)&Ot[l31*64 + (d0 ^ ((l31 & 7) << 3))] = pw;
        }

    int b = bh >> 4, h = bh & 15;
    int q2 = l >> 1, dh = (l & 1) * 32;
    size_t obase = ((size_t)(b*SSEQ) + q0 + w*32 + q2)*EMBED + h*HDIM;
    #pragma unroll
    for (int j = 0; j < 4; j++) {
        int d = dh + j*8;
        short8 ov = *(short8*)&Ot[q2*64 + (d ^ ((q2 & 7) << 3))];
        *(short8*)&o[obase + d] = ov;
    }
}

extern "C" void kernel_launch(void* const* d_in, const int* in_sizes, int n_in,
                              void* d_out, int out_size, void* d_ws, size_t ws_size,
                              hipStream_t stream) {
    const float* x  = (const float*)d_in[0];
    const float* Wq = (const float*)d_in[1];
    const float* bq = (const float*)d_in[2];
    const float* Wk = (const float*)d_in[3];
    const float* bk = (const float*)d_in[4];
    const float* Wv = (const float*)d_in[5];
    const float* bv = (const float*)d_in[6];
    const float* Wo = (const float*)d_in[7];
    const float* bo = (const float*)d_in[8];

    char* ws = (char*)d_ws;
    ushort_t* xb  = (ushort_t*)(ws);                    // 0-8 MB: x bf16, later reused as attn-out
    ushort_t* WqT = (ushort_t*)(ws + (8u  << 20));      // WqT|WkT|WvT contiguous [3072][1024]
    ushort_t* WkT = (ushort_t*)(ws + (10u << 20));
    ushort_t* WvT = (ushort_t*)(ws + (12u << 20));
    ushort_t* WoT = (ushort_t*)(ws + (14u << 20));
    ushort_t* qb  = (ushort_t*)(ws + (16u << 20));      // q|k contiguous, 8 MB each
    ushort_t* kb  = (ushort_t*)(ws + (24u << 20));
    ushort_t* vtb = (ushort_t*)(ws + (40u << 20));      // V transposed [B,H,D,S] (written by GEMM)
    ushort_t* ab  = xb;
    (void)kb;

    int nx = MROWS * EMBED;
    cast_bf16_kernel<<<nx/(256*4), 256, 0, stream>>>(x, xb, nx);

    transpose_cast4_kernel<<<dim3(EMBED/32, EMBED/32, 4), dim3(32, 8), 0, stream>>>(
        Wq, Wk, Wv, Wo, WqT, WkT, WvT, WoT);

    gemm_qkv_256_kernel<<<dim3(QKV_N/256, MROWS/256), 512, 0, stream>>>(
        xb, WqT, bq, bk, bv, qb, vtb);

    flash_attn2_kernel<<<256, 512, 0, stream>>>(qb, kb, vtb, ab);

    gemm_out_kernel<<<dim3(EMBED/128, MROWS/128), 256, 0, stream>>>(
        ab, WoT, bo, (float*)d_out, MROWS, EMBED, EMBED);
}

// Round 20
// 120.831 us; speedup vs baseline: 1.0534x; 1.0534x over previous
//
#include <hip/hip_runtime.h>
#include <hip/hip_bf16.h>

typedef unsigned short ushort_t;
typedef __attribute__((ext_vector_type(4))) short short4v;
typedef __attribute__((ext_vector_type(8))) short short8;
typedef __attribute__((ext_vector_type(4))) float f32x4;
typedef __attribute__((ext_vector_type(16))) float f32x16;
typedef __attribute__((ext_vector_type(2))) unsigned int uint2v;

#define EMBED 1024
#define NHEAD 16
#define HDIM 64
#define BB 2
#define SSEQ 2048
#define MROWS (BB*SSEQ)          // 4096
#define QKV_N (3*EMBED)          // 3072
#define PER_BUF (MROWS*EMBED)    // 4194304 elems = 8MB bf16

__device__ __forceinline__ ushort_t f2bf(float f) {
    union { float f; unsigned int u; } x; x.f = f;
    unsigned int r = x.u + 0x7fffu + ((x.u >> 16) & 1u);
    return (ushort_t)(r >> 16);
}
// HW packed f32x2 -> bf16x2 (RNE), single VALU op
__device__ __forceinline__ unsigned cvt_pk_bf16(float lo, float hi) {
    unsigned r;
    asm("v_cvt_pk_bf16_f32 %0, %1, %2" : "=v"(r) : "v"(lo), "v"(hi));
    return r;
}

__device__ __forceinline__ void gload16(const void* g, void* l) {
    __builtin_amdgcn_global_load_lds(
        (const __attribute__((address_space(1))) unsigned int*)g,
        (__attribute__((address_space(3))) unsigned int*)l, 16, 0, 0);
}

// ---------------- cast x (fp32 -> bf16), vectorized ----------------
__global__ void cast_bf16_kernel(const float* __restrict__ in, ushort_t* __restrict__ out, int n) {
    int i = (blockIdx.x * blockDim.x + threadIdx.x) * 4;
    if (i + 3 < n) {
        float4 v = *(const float4*)(in + i);
        out[i+0] = f2bf(v.x); out[i+1] = f2bf(v.y);
        out[i+2] = f2bf(v.z); out[i+3] = f2bf(v.w);
    }
}

// ---------------- 4x W [K,N] fp32 -> Wt [N,K] bf16, one launch ----------------
__global__ void transpose_cast4_kernel(
    const float* __restrict__ W0, const float* __restrict__ W1,
    const float* __restrict__ W2, const float* __restrict__ W3,
    ushort_t* __restrict__ T0, ushort_t* __restrict__ T1,
    ushort_t* __restrict__ T2, ushort_t* __restrict__ T3)
{
    __shared__ float tile[32][33];
    int z = blockIdx.z;
    const float* W = (z == 0) ? W0 : (z == 1) ? W1 : (z == 2) ? W2 : W3;
    ushort_t* Wt   = (z == 0) ? T0 : (z == 1) ? T1 : (z == 2) ? T2 : T3;
    int tx = threadIdx.x, ty = threadIdx.y;   // 32 x 8
    int n0 = blockIdx.x * 32, k0 = blockIdx.y * 32;
    #pragma unroll
    for (int i = 0; i < 4; i++)
        tile[ty*4+i][tx] = W[(size_t)(k0 + ty*4 + i) * EMBED + n0 + tx];
    __syncthreads();
    #pragma unroll
    for (int i = 0; i < 4; i++)
        Wt[(size_t)(n0 + ty*4 + i) * EMBED + k0 + tx] = f2bf(tile[tx][ty*4+i]);
}

// ---------------- GEMM: C[M,N] = A[M,K] * Bt[N,K]^T + bias (r13 BK=64) ----------------
// OUT_MODE 0: fp32 row-major C (bias b0).
// OUT_MODE 2: q/k -> [B,H,S,Dh] (q pre-scaled by 0.125*log2e); V -> vt_out [B,H,D,S] directly.
template<int OUT_MODE>
__global__ __launch_bounds__(256) void gemm_bt_kernel(
    const ushort_t* __restrict__ A,   // [M,K] bf16
    const ushort_t* __restrict__ Bt,  // [N,K] bf16
    const float* __restrict__ b0, const float* __restrict__ b1, const float* __restrict__ b2,
    void* __restrict__ Cout,
    ushort_t* __restrict__ vt_out,
    int M, int N, int K)
{
    __shared__ __attribute__((aligned(16))) ushort_t Asm[128*64];
    __shared__ __attribute__((aligned(16))) ushort_t Bsm[128*64];
    int t = threadIdx.x;
    int w = t >> 6, l = t & 63;
    int wr = w >> 1, wc = w & 1;
    int lrow = l & 15, lhi = l >> 4;

    // XCD-chunked bijective swizzle (nwg % 8 == 0)
    int gx = gridDim.x;
    int flat = blockIdx.y * gx + blockIdx.x;
    int q8 = (gx * gridDim.y) >> 3;
    int nf = (flat & 7) * q8 + (flat >> 3);
    int m0 = (nf / gx) * 128, n0 = (nf % gx) * 128;

    int srow8 = l >> 3;                       // 0..7 row within 8-row chunk
    int colel = 8 * ((l & 7) ^ srow8);        // pre-swizzled global column (elems)

    f32x4 acc[4][4];
    #pragma unroll
    for (int mi = 0; mi < 4; mi++)
        #pragma unroll
        for (int ni = 0; ni < 4; ni++)
            #pragma unroll
            for (int c = 0; c < 4; c++) acc[mi][ni][c] = 0.f;

    for (int k0 = 0; k0 < K; k0 += 64) {
        __syncthreads();
        #pragma unroll
        for (int p = 0; p < 4; p++) {
            int row = w*32 + p*8 + srow8;
            gload16(&A [(size_t)(m0 + row)*K + k0 + colel], &Asm[(w*32 + p*8)*64]);
            gload16(&Bt[(size_t)(n0 + row)*K + k0 + colel], &Bsm[(w*32 + p*8)*64]);
        }
        __syncthreads();
        #pragma unroll
        for (int kk = 0; kk < 2; kk++) {
            short8 af[4], bfr[4];
            #pragma unroll
            for (int mi = 0; mi < 4; mi++) {
                int r = wr*64 + mi*16 + lrow;
                af[mi] = *(short8*)&Asm[r*64 + ((kk*32 + lhi*8) ^ ((r & 7) << 3))];
            }
            #pragma unroll
            for (int ni = 0; ni < 4; ni++) {
                int r = wc*64 + ni*16 + lrow;
                bfr[ni] = *(short8*)&Bsm[r*64 + ((kk*32 + lhi*8) ^ ((r & 7) << 3))];
            }
            __builtin_amdgcn_s_setprio(1);
            #pragma unroll
            for (int mi = 0; mi < 4; mi++)
                #pragma unroll
                for (int ni = 0; ni < 4; ni++)
                    acc[mi][ni] = __builtin_amdgcn_mfma_f32_16x16x32_bf16(af[mi], bfr[ni], acc[mi][ni], 0, 0, 0);
            __builtin_amdgcn_s_setprio(0);
        }
    }

    #pragma unroll
    for (int mi = 0; mi < 4; mi++)
        #pragma unroll
        for (int ni = 0; ni < 4; ni++) {
            int col = n0 + wc*64 + ni*16 + lrow;
            if (OUT_MODE == 2 && (col >> 10) == 2) {
                // V: write transposed [B,H,D,S] directly, 8B per thread (4 consecutive s)
                int hc = col & 1023;
                int h = hc >> 6, d = hc & 63;
                int row0 = m0 + wr*64 + mi*16 + lhi*4;
                int b = row0 >> 11, s0 = row0 & 2047;
                int bh = b*NHEAD + h;
                short4v pk;
                #pragma unroll
                for (int c = 0; c < 4; c++)
                    pk[c] = (short)f2bf(acc[mi][ni][c] + b2[hc]);
                *(short4v*)&vt_out[((size_t)bh*HDIM + d)*SSEQ + s0] = pk;
            } else {
                #pragma unroll
                for (int c = 0; c < 4; c++) {
                    int row = m0 + wr*64 + mi*16 + lhi*4 + c;
                    if (OUT_MODE == 0) {
                        float v = acc[mi][ni][c] + b0[col];
                        ((float*)Cout)[(size_t)row * N + col] = v;
                    } else {
                        int which = col >> 10, hc = col & 1023;
                        const float* bp = (which == 0) ? b0 : b1;
                        float v = acc[mi][ni][c] + bp[hc];
                        if (which == 0) v *= 0.18033688011112042f;  // 0.125 * log2(e)
                        int h = hc >> 6, d = hc & 63;
                        int b = row >> 11, s = row & 2047;
                        ((ushort_t*)Cout)[(size_t)which*PER_BUF + ((size_t)((b*NHEAD + h)*SSEQ) + s)*HDIM + d] = f2bf(v);
                    }
                }
            }
        }
}

// ---------------- flash attention v2e: r15 body, 8-wave blocks (QBLK=256) ----------------
// q: [B,H,S,D] bf16 pre-scaled by 0.125*log2e; k: [B,H,S,D]; vt: [B,H,D,S]; o: [B,S,E] bf16
#define MFMA32(a,b,c) __builtin_amdgcn_mfma_f32_32x32x16_bf16(a, b, c, 0, 0, 0)

__global__ __launch_bounds__(512, 1) void flash_attn2_kernel(
    const ushort_t* __restrict__ q,
    const ushort_t* __restrict__ k,
    const ushort_t* __restrict__ vt,
    ushort_t* __restrict__ o)
{
    __shared__ __attribute__((aligned(16))) ushort_t Ks[2][2][64*64];  // [buf][sub][kv64][d64] swz
    __shared__ __attribute__((aligned(16))) ushort_t Vs[2][2][64*64];  // [buf][sub][d64][kv64] swz

    int t = threadIdx.x, w = t >> 6, l = t & 63;   // w in 0..7
    int l31 = l & 31, hi = l >> 5;

    // XCD-bijective swizzle: 256 wgs, 32/XCD -> 4 whole heads per XCD L2
    int flat = blockIdx.x;
    int wg = (flat & 7) * 32 + (flat >> 3);
    int bh = wg >> 3;
    int q0 = (wg & 7) * 256;

    const ushort_t* qp = q  + (size_t)bh * SSEQ * HDIM;
    const ushort_t* kp = k  + (size_t)bh * SSEQ * HDIM;
    const ushort_t* vp = vt + (size_t)bh * HDIM * SSEQ;

    int lr = l >> 3, lc = l & 7;
    int colel = 8 * (lc ^ lr);   // pre-swizzled global column for staging

    // Q fragments (B-operand): lane holds Q[q0 + w*32 + l31][st*16 + hi*8 + j]
    short8 qf[4];
    int qrow = q0 + w*32 + l31;
    #pragma unroll
    for (int st = 0; st < 4; st++)
        qf[st] = *(const short8*)&qp[(size_t)qrow*HDIM + st*16 + hi*8];

    f32x16 o0 = {}, o1 = {};
    float m_run = -1e30f, l_run = 0.f;

    // stage K rows / Vt rows of BOTH 64-subtiles; 8 waves x 8 rows cover each 64-row subtile
    #define STAGE(buf, kv0) { \
        _Pragma("unroll") \
        for (int sub = 0; sub < 2; sub++) { \
            int row = w*8 + lr; \
            gload16(&kp[(size_t)(kv0 + sub*64 + row)*HDIM + colel], &Ks[buf][sub][(w*8)*64]); \
            gload16(&vp[(size_t)row*SSEQ + (kv0) + sub*64 + colel], &Vs[buf][sub][(w*8)*64]); \
        } }

    STAGE(0, 0)
    asm volatile("s_waitcnt vmcnt(0)");
    __syncthreads();
    int cur = 0;

    for (int kv0 = 0; kv0 < SSEQ; kv0 += 128) {
        if (kv0 + 128 < SSEQ) { STAGE(cur ^ 1, kv0 + 128) }

        // ---- S^T = K @ Q^T : s_kt holds S[q=l31][kv = crow(r,hi) + 32*kt]
        f32x16 s0 = {}, s1 = {}, s2 = {}, s3 = {};
        __builtin_amdgcn_s_setprio(1);
        #pragma unroll
        for (int st = 0; st < 4; st++) {
            int colb = st*16 + hi*8;
            int sw0 = colb ^ ((l31 & 7) << 3);
            short8 kf0 = *(const short8*)&Ks[cur][0][l31*64        + sw0];
            short8 kf1 = *(const short8*)&Ks[cur][0][(32 + l31)*64 + sw0];
            short8 kf2 = *(const short8*)&Ks[cur][1][l31*64        + sw0];
            short8 kf3 = *(const short8*)&Ks[cur][1][(32 + l31)*64 + sw0];
            s0 = MFMA32(kf0, qf[st], s0);
            s1 = MFMA32(kf1, qf[st], s1);
            s2 = MFMA32(kf2, qf[st], s2);
            s3 = MFMA32(kf3, qf[st], s3);
        }
        __builtin_amdgcn_s_setprio(0);

        // ---- online softmax (log2 domain), per-lane rows; 4-chain tree max over 64 vals
        float ma = fmaxf(s0[0], s0[1]);
        float mb = fmaxf(s0[2], s0[3]);
        float mc = fmaxf(s0[4], s0[5]);
        float md = fmaxf(s0[6], s0[7]);
        ma = fmaxf(fmaxf(ma, s0[8]),  s0[9]);
        mb = fmaxf(fmaxf(mb, s0[10]), s0[11]);
        mc = fmaxf(fmaxf(mc, s0[12]), s0[13]);
        md = fmaxf(fmaxf(md, s0[14]), s0[15]);
        ma = fmaxf(fmaxf(ma, s1[0]),  s1[1]);
        mb = fmaxf(fmaxf(mb, s1[2]),  s1[3]);
        mc = fmaxf(fmaxf(mc, s1[4]),  s1[5]);
        md = fmaxf(fmaxf(md, s1[6]),  s1[7]);
        ma = fmaxf(fmaxf(ma, s1[8]),  s1[9]);
        mb = fmaxf(fmaxf(mb, s1[10]), s1[11]);
        mc = fmaxf(fmaxf(mc, s1[12]), s1[13]);
        md = fmaxf(fmaxf(md, s1[14]), s1[15]);
        ma = fmaxf(fmaxf(ma, s2[0]),  s2[1]);
        mb = fmaxf(fmaxf(mb, s2[2]),  s2[3]);
        mc = fmaxf(fmaxf(mc, s2[4]),  s2[5]);
        md = fmaxf(fmaxf(md, s2[6]),  s2[7]);
        ma = fmaxf(fmaxf(ma, s2[8]),  s2[9]);
        mb = fmaxf(fmaxf(mb, s2[10]), s2[11]);
        mc = fmaxf(fmaxf(mc, s2[12]), s2[13]);
        md = fmaxf(fmaxf(md, s2[14]), s2[15]);
        ma = fmaxf(fmaxf(ma, s3[0]),  s3[1]);
        mb = fmaxf(fmaxf(mb, s3[2]),  s3[3]);
        mc = fmaxf(fmaxf(mc, s3[4]),  s3[5]);
        md = fmaxf(fmaxf(md, s3[6]),  s3[7]);
        ma = fmaxf(fmaxf(ma, s3[8]),  s3[9]);
        mb = fmaxf(fmaxf(mb, s3[10]), s3[11]);
        mc = fmaxf(fmaxf(mc, s3[12]), s3[13]);
        md = fmaxf(fmaxf(md, s3[14]), s3[15]);
        float mx = fmaxf(fmaxf(ma, mb), fmaxf(mc, md));
        mx = fmaxf(mx, __shfl_xor(mx, 32));

        if (__any(mx > m_run + 8.f)) {       // defer-max (T13)
            float mnew = fmaxf(m_run, mx);
            float alpha = __builtin_amdgcn_exp2f(m_run - mnew);
            #pragma unroll
            for (int r = 0; r < 16; r++) { o0[r] *= alpha; o1[r] *= alpha; }
            l_run *= alpha;
            m_run = mnew;
        }
        float r0 = 0.f, r1 = 0.f, r2 = 0.f, r3 = 0.f;
        #pragma unroll
        for (int r = 0; r < 16; r += 4) {
            s0[r]   = __builtin_amdgcn_exp2f(s0[r]   - m_run); r0 += s0[r];
            s0[r+1] = __builtin_amdgcn_exp2f(s0[r+1] - m_run); r1 += s0[r+1];
            s0[r+2] = __builtin_amdgcn_exp2f(s0[r+2] - m_run); r2 += s0[r+2];
            s0[r+3] = __builtin_amdgcn_exp2f(s0[r+3] - m_run); r3 += s0[r+3];
        }
        #pragma unroll
        for (int r = 0; r < 16; r += 4) {
            s1[r]   = __builtin_amdgcn_exp2f(s1[r]   - m_run); r0 += s1[r];
            s1[r+1] = __builtin_amdgcn_exp2f(s1[r+1] - m_run); r1 += s1[r+1];
            s1[r+2] = __builtin_amdgcn_exp2f(s1[r+2] - m_run); r2 += s1[r+2];
            s1[r+3] = __builtin_amdgcn_exp2f(s1[r+3] - m_run); r3 += s1[r+3];
        }
        #pragma unroll
        for (int r = 0; r < 16; r += 4) {
            s2[r]   = __builtin_amdgcn_exp2f(s2[r]   - m_run); r0 += s2[r];
            s2[r+1] = __builtin_amdgcn_exp2f(s2[r+1] - m_run); r1 += s2[r+1];
            s2[r+2] = __builtin_amdgcn_exp2f(s2[r+2] - m_run); r2 += s2[r+2];
            s2[r+3] = __builtin_amdgcn_exp2f(s2[r+3] - m_run); r3 += s2[r+3];
        }
        #pragma unroll
        for (int r = 0; r < 16; r += 4) {
            s3[r]   = __builtin_amdgcn_exp2f(s3[r]   - m_run); r0 += s3[r];
            s3[r+1] = __builtin_amdgcn_exp2f(s3[r+1] - m_run); r1 += s3[r+1];
            s3[r+2] = __builtin_amdgcn_exp2f(s3[r+2] - m_run); r2 += s3[r+2];
            s3[r+3] = __builtin_amdgcn_exp2f(s3[r+3] - m_run); r3 += s3[r+3];
        }
        float rs = (r0 + r1) + (r2 + r3);
        rs += __shfl_xor(rs, 32);
        l_run += rs;

        // ---- P -> bf16 B-fragments via v_cvt_pk_bf16_f32 + permlane32_swap (T12)
        // pfr[ks][j] = P[q=l31][kv = 16*ks + 8*hi + j], ks = 2*acc + sub
        short8 pfr[8];
        #define PACK8(SV, KS0) { \
            unsigned a0 = cvt_pk_bf16(SV[0], SV[1]); \
            unsigned a1 = cvt_pk_bf16(SV[2], SV[3]); \
            unsigned b0 = cvt_pk_bf16(SV[4], SV[5]); \
            unsigned b1 = cvt_pk_bf16(SV[6], SV[7]); \
            uint2v rr0 = __builtin_amdgcn_permlane32_swap(a0, b0, false, false); \
            uint2v rr1 = __builtin_amdgcn_permlane32_swap(a1, b1, false, false); \
            union { unsigned u[4]; short8 v; } pfa; \
            pfa.u[0] = rr0.x; pfa.u[1] = rr1.x; pfa.u[2] = rr0.y; pfa.u[3] = rr1.y; \
            pfr[KS0] = pfa.v; \
            unsigned c0 = cvt_pk_bf16(SV[8], SV[9]); \
            unsigned c1 = cvt_pk_bf16(SV[10], SV[11]); \
            unsigned d0 = cvt_pk_bf16(SV[12], SV[13]); \
            unsigned d1 = cvt_pk_bf16(SV[14], SV[15]); \
            uint2v rr2 = __builtin_amdgcn_permlane32_swap(c0, d0, false, false); \
            uint2v rr3 = __builtin_amdgcn_permlane32_swap(c1, d1, false, false); \
            union { unsigned u[4]; short8 v; } pfb; \
            pfb.u[0] = rr2.x; pfb.u[1] = rr3.x; pfb.u[2] = rr2.y; pfb.u[3] = rr3.y; \
            pfr[(KS0)+1] = pfb.v; \
        }
        PACK8(s0, 0)
        PACK8(s1, 2)
        PACK8(s2, 4)
        PACK8(s3, 6)
        #undef PACK8

        // ---- O^T += V^T P^T : lane holds O[q=l31][d=crow(r,hi)+32*dt]
        __builtin_amdgcn_s_setprio(1);
        #pragma unroll
        for (int ks = 0; ks < 8; ks++) {
            int sub = ks >> 2;
            int colb = (ks & 3)*16 + hi*8;
            int sw = colb ^ ((l31 & 7) << 3);
            short8 vf0 = *(const short8*)&Vs[cur][sub][l31*64        + sw];
            short8 vf1 = *(const short8*)&Vs[cur][sub][(32 + l31)*64 + sw];
            o0 = MFMA32(vf0, pfr[ks], o0);
            o1 = MFMA32(vf1, pfr[ks], o1);
        }
        __builtin_amdgcn_s_setprio(0);

        asm volatile("s_waitcnt vmcnt(0)");
        __syncthreads();
        cur ^= 1;
    }

    // ---- epilogue: normalize, LDS roundtrip for coalesced stores (8 x 4KB = all of Ks)
    float rl = 1.f / l_run;
    ushort_t* Ot = ((ushort_t*)Ks) + w*(32*64);
    #pragma unroll
    for (int dt = 0; dt < 2; dt++)
        #pragma unroll
        for (int rq = 0; rq < 4; rq++) {
            float v0 = (dt ? o1[rq*4+0] : o0[rq*4+0]) * rl;
            float v1 = (dt ? o1[rq*4+1] : o0[rq*4+1]) * rl;
            float v2 = (dt ? o1[rq*4+2] : o0[rq*4+2]) * rl;
            float v3 = (dt ? o1[rq*4+3] : o0[rq*4+3]) * rl;
            int d0 = dt*32 + rq*8 + hi*4;
            uint2v pw = { cvt_pk_bf16(v0, v1), cvt_pk_bf16(v2, v3) };
            *(uint2v*)&Ot[l31*64 + (d0 ^ ((l31 & 7) << 3))] = pw;
        }

    int b = bh >> 4, h = bh & 15;
    int q2 = l >> 1, dh = (l & 1) * 32;
    size_t obase = ((size_t)(b*SSEQ) + q0 + w*32 + q2)*EMBED + h*HDIM;
    #pragma unroll
    for (int j = 0; j < 4; j++) {
        int d = dh + j*8;
        short8 ov = *(short8*)&Ot[q2*64 + (d ^ ((q2 & 7) << 3))];
        *(short8*)&o[obase + d] = ov;
    }
}

extern "C" void kernel_launch(void* const* d_in, const int* in_sizes, int n_in,
                              void* d_out, int out_size, void* d_ws, size_t ws_size,
                              hipStream_t stream) {
    const float* x  = (const float*)d_in[0];
    const float* Wq = (const float*)d_in[1];
    const float* bq = (const float*)d_in[2];
    const float* Wk = (const float*)d_in[3];
    const float* bk = (const float*)d_in[4];
    const float* Wv = (const float*)d_in[5];
    const float* bv = (const float*)d_in[6];
    const float* Wo = (const float*)d_in[7];
    const float* bo = (const float*)d_in[8];

    char* ws = (char*)d_ws;
    ushort_t* xb  = (ushort_t*)(ws);                    // 0-8 MB: x bf16, later reused as attn-out
    ushort_t* WqT = (ushort_t*)(ws + (8u  << 20));      // WqT|WkT|WvT contiguous [3072][1024]
    ushort_t* WkT = (ushort_t*)(ws + (10u << 20));
    ushort_t* WvT = (ushort_t*)(ws + (12u << 20));
    ushort_t* WoT = (ushort_t*)(ws + (14u << 20));
    ushort_t* qb  = (ushort_t*)(ws + (16u << 20));      // q|k contiguous, 8 MB each
    ushort_t* kb  = (ushort_t*)(ws + (24u << 20));
    ushort_t* vtb = (ushort_t*)(ws + (40u << 20));      // V transposed [B,H,D,S] (written by GEMM)
    ushort_t* ab  = xb;

    int nx = MROWS * EMBED;
    cast_bf16_kernel<<<nx/(256*4), 256, 0, stream>>>(x, xb, nx);

    transpose_cast4_kernel<<<dim3(EMBED/32, EMBED/32, 4), dim3(32, 8), 0, stream>>>(
        Wq, Wk, Wv, Wo, WqT, WkT, WvT, WoT);

    gemm_bt_kernel<2><<<dim3(QKV_N/128, MROWS/128), 256, 0, stream>>>(
        xb, WqT, bq, bk, bv, qb, vtb, MROWS, QKV_N, EMBED);

    flash_attn2_kernel<<<256, 512, 0, stream>>>(qb, kb, vtb, ab);

    gemm_bt_kernel<0><<<dim3(EMBED/128, MROWS/128), 256, 0, stream>>>(
        ab, WoT, bo, bo, bo, d_out, nullptr, MROWS, EMBED, EMBED);
}

// Round 21
// 118.046 us; speedup vs baseline: 1.0782x; 1.0236x over previous
//
#include <hip/hip_runtime.h>
#include <hip/hip_bf16.h>

typedef unsigned short ushort_t;
typedef __attribute__((ext_vector_type(4))) short short4v;
typedef __attribute__((ext_vector_type(8))) short short8;
typedef __attribute__((ext_vector_type(4))) float f32x4;
typedef __attribute__((ext_vector_type(16))) float f32x16;
typedef __attribute__((ext_vector_type(2))) unsigned int uint2v;

#define EMBED 1024
#define NHEAD 16
#define HDIM 64
#define BB 2
#define SSEQ 2048
#define MROWS (BB*SSEQ)          // 4096
#define QKV_N (3*EMBED)          // 3072
#define PER_BUF (MROWS*EMBED)    // 4194304 elems = 8MB bf16

__device__ __forceinline__ ushort_t f2bf(float f) {
    union { float f; unsigned int u; } x; x.f = f;
    unsigned int r = x.u + 0x7fffu + ((x.u >> 16) & 1u);
    return (ushort_t)(r >> 16);
}
// HW packed f32x2 -> bf16x2 (RNE), single VALU op
__device__ __forceinline__ unsigned cvt_pk_bf16(float lo, float hi) {
    unsigned r;
    asm("v_cvt_pk_bf16_f32 %0, %1, %2" : "=v"(r) : "v"(lo), "v"(hi));
    return r;
}

__device__ __forceinline__ void gload16(const void* g, void* l) {
    __builtin_amdgcn_global_load_lds(
        (const __attribute__((address_space(1))) unsigned int*)g,
        (__attribute__((address_space(3))) unsigned int*)l, 16, 0, 0);
}

// ---------------- fused prep: z<4 -> W transpose+cast; z==4 -> x cast ----------------
__global__ void prep_kernel(
    const float* __restrict__ x, ushort_t* __restrict__ xb,
    const float* __restrict__ W0, const float* __restrict__ W1,
    const float* __restrict__ W2, const float* __restrict__ W3,
    ushort_t* __restrict__ T0, ushort_t* __restrict__ T1,
    ushort_t* __restrict__ T2, ushort_t* __restrict__ T3)
{
    int z = blockIdx.z;
    if (z == 4) {
        // cast x: 1024 blocks x 256 thr x 16 elems = 4M
        int t = threadIdx.y * 32 + threadIdx.x;
        int idx = (blockIdx.y * 32 + blockIdx.x) * 256 + t;
        int i = idx * 16;
        #pragma unroll
        for (int p = 0; p < 4; p++) {
            float4 v = *(const float4*)(x + i + p*4);
            xb[i + p*4 + 0] = f2bf(v.x); xb[i + p*4 + 1] = f2bf(v.y);
            xb[i + p*4 + 2] = f2bf(v.z); xb[i + p*4 + 3] = f2bf(v.w);
        }
        return;
    }
    __shared__ float tile[32][33];
    const float* W = (z == 0) ? W0 : (z == 1) ? W1 : (z == 2) ? W2 : W3;
    ushort_t* Wt   = (z == 0) ? T0 : (z == 1) ? T1 : (z == 2) ? T2 : T3;
    int tx = threadIdx.x, ty = threadIdx.y;   // 32 x 8
    int n0 = blockIdx.x * 32, k0 = blockIdx.y * 32;
    #pragma unroll
    for (int i = 0; i < 4; i++)
        tile[ty*4+i][tx] = W[(size_t)(k0 + ty*4 + i) * EMBED + n0 + tx];
    __syncthreads();
    #pragma unroll
    for (int i = 0; i < 4; i++)
        Wt[(size_t)(n0 + ty*4 + i) * EMBED + k0 + tx] = f2bf(tile[tx][ty*4+i]);
}

// ---------------- GEMM: C[M,N] = A[M,K] * Bt[N,K]^T + bias (r13 BK=64) ----------------
// OUT_MODE 0: fp32 row-major C (bias b0).
// OUT_MODE 2: q/k -> [B,H,S,Dh] (q pre-scaled by 0.125*log2e); V -> vt_out [B,H,D,S] directly.
template<int OUT_MODE>
__global__ __launch_bounds__(256) void gemm_bt_kernel(
    const ushort_t* __restrict__ A,   // [M,K] bf16
    const ushort_t* __restrict__ Bt,  // [N,K] bf16
    const float* __restrict__ b0, const float* __restrict__ b1, const float* __restrict__ b2,
    void* __restrict__ Cout,
    ushort_t* __restrict__ vt_out,
    int M, int N, int K)
{
    __shared__ __attribute__((aligned(16))) ushort_t Asm[128*64];
    __shared__ __attribute__((aligned(16))) ushort_t Bsm[128*64];
    int t = threadIdx.x;
    int w = t >> 6, l = t & 63;
    int wr = w >> 1, wc = w & 1;
    int lrow = l & 15, lhi = l >> 4;

    // XCD-chunked bijective swizzle (nwg % 8 == 0)
    int gx = gridDim.x;
    int flat = blockIdx.y * gx + blockIdx.x;
    int q8 = (gx * gridDim.y) >> 3;
    int nf = (flat & 7) * q8 + (flat >> 3);
    int m0 = (nf / gx) * 128, n0 = (nf % gx) * 128;

    int srow8 = l >> 3;                       // 0..7 row within 8-row chunk
    int colel = 8 * ((l & 7) ^ srow8);        // pre-swizzled global column (elems)

    f32x4 acc[4][4];
    #pragma unroll
    for (int mi = 0; mi < 4; mi++)
        #pragma unroll
        for (int ni = 0; ni < 4; ni++)
            #pragma unroll
            for (int c = 0; c < 4; c++) acc[mi][ni][c] = 0.f;

    for (int k0 = 0; k0 < K; k0 += 64) {
        __syncthreads();
        #pragma unroll
        for (int p = 0; p < 4; p++) {
            int row = w*32 + p*8 + srow8;
            gload16(&A [(size_t)(m0 + row)*K + k0 + colel], &Asm[(w*32 + p*8)*64]);
            gload16(&Bt[(size_t)(n0 + row)*K + k0 + colel], &Bsm[(w*32 + p*8)*64]);
        }
        __syncthreads();
        #pragma unroll
        for (int kk = 0; kk < 2; kk++) {
            short8 af[4], bfr[4];
            #pragma unroll
            for (int mi = 0; mi < 4; mi++) {
                int r = wr*64 + mi*16 + lrow;
                af[mi] = *(short8*)&Asm[r*64 + ((kk*32 + lhi*8) ^ ((r & 7) << 3))];
            }
            #pragma unroll
            for (int ni = 0; ni < 4; ni++) {
                int r = wc*64 + ni*16 + lrow;
                bfr[ni] = *(short8*)&Bsm[r*64 + ((kk*32 + lhi*8) ^ ((r & 7) << 3))];
            }
            __builtin_amdgcn_s_setprio(1);
            #pragma unroll
            for (int mi = 0; mi < 4; mi++)
                #pragma unroll
                for (int ni = 0; ni < 4; ni++)
                    acc[mi][ni] = __builtin_amdgcn_mfma_f32_16x16x32_bf16(af[mi], bfr[ni], acc[mi][ni], 0, 0, 0);
            __builtin_amdgcn_s_setprio(0);
        }
    }

    #pragma unroll
    for (int mi = 0; mi < 4; mi++)
        #pragma unroll
        for (int ni = 0; ni < 4; ni++) {
            int col = n0 + wc*64 + ni*16 + lrow;
            if (OUT_MODE == 2 && (col >> 10) == 2) {
                // V: write transposed [B,H,D,S] directly, 8B per thread (4 consecutive s)
                int hc = col & 1023;
                int h = hc >> 6, d = hc & 63;
                int row0 = m0 + wr*64 + mi*16 + lhi*4;
                int b = row0 >> 11, s0 = row0 & 2047;
                int bh = b*NHEAD + h;
                short4v pk;
                #pragma unroll
                for (int c = 0; c < 4; c++)
                    pk[c] = (short)f2bf(acc[mi][ni][c] + b2[hc]);
                *(short4v*)&vt_out[((size_t)bh*HDIM + d)*SSEQ + s0] = pk;
            } else {
                #pragma unroll
                for (int c = 0; c < 4; c++) {
                    int row = m0 + wr*64 + mi*16 + lhi*4 + c;
                    if (OUT_MODE == 0) {
                        float v = acc[mi][ni][c] + b0[col];
                        ((float*)Cout)[(size_t)row * N + col] = v;
                    } else {
                        int which = col >> 10, hc = col & 1023;
                        const float* bp = (which == 0) ? b0 : b1;
                        float v = acc[mi][ni][c] + bp[hc];
                        if (which == 0) v *= 0.18033688011112042f;  // 0.125 * log2(e)
                        int h = hc >> 6, d = hc & 63;
                        int b = row >> 11, s = row & 2047;
                        ((ushort_t*)Cout)[(size_t)which*PER_BUF + ((size_t)((b*NHEAD + h)*SSEQ) + s)*HDIM + d] = f2bf(v);
                    }
                }
            }
        }
}

// ---------------- flash attention v2e (proven r18/r20): 8-wave blocks, QBLK=256, KVBLK=128 ----------------
#define MFMA32(a,b,c) __builtin_amdgcn_mfma_f32_32x32x16_bf16(a, b, c, 0, 0, 0)

__global__ __launch_bounds__(512, 1) void flash_attn2_kernel(
    const ushort_t* __restrict__ q,
    const ushort_t* __restrict__ k,
    const ushort_t* __restrict__ vt,
    ushort_t* __restrict__ o)
{
    __shared__ __attribute__((aligned(16))) ushort_t Ks[2][2][64*64];  // [buf][sub][kv64][d64] swz
    __shared__ __attribute__((aligned(16))) ushort_t Vs[2][2][64*64];  // [buf][sub][d64][kv64] swz

    int t = threadIdx.x, w = t >> 6, l = t & 63;   // w in 0..7
    int l31 = l & 31, hi = l >> 5;

    // XCD-bijective swizzle: 256 wgs, 32/XCD -> 4 whole heads per XCD L2
    int flat = blockIdx.x;
    int wg = (flat & 7) * 32 + (flat >> 3);
    int bh = wg >> 3;
    int q0 = (wg & 7) * 256;

    const ushort_t* qp = q  + (size_t)bh * SSEQ * HDIM;
    const ushort_t* kp = k  + (size_t)bh * SSEQ * HDIM;
    const ushort_t* vp = vt + (size_t)bh * HDIM * SSEQ;

    int lr = l >> 3, lc = l & 7;
    int colel = 8 * (lc ^ lr);   // pre-swizzled global column for staging

    // Q fragments (B-operand): lane holds Q[q0 + w*32 + l31][st*16 + hi*8 + j]
    short8 qf[4];
    int qrow = q0 + w*32 + l31;
    #pragma unroll
    for (int st = 0; st < 4; st++)
        qf[st] = *(const short8*)&qp[(size_t)qrow*HDIM + st*16 + hi*8];

    f32x16 o0 = {}, o1 = {};
    float m_run = -1e30f, l_run = 0.f;

    // stage K rows / Vt rows of BOTH 64-subtiles; 8 waves x 8 rows cover each 64-row subtile
    #define STAGE(buf, kv0) { \
        _Pragma("unroll") \
        for (int sub = 0; sub < 2; sub++) { \
            int row = w*8 + lr; \
            gload16(&kp[(size_t)(kv0 + sub*64 + row)*HDIM + colel], &Ks[buf][sub][(w*8)*64]); \
            gload16(&vp[(size_t)row*SSEQ + (kv0) + sub*64 + colel], &Vs[buf][sub][(w*8)*64]); \
        } }

    STAGE(0, 0)
    asm volatile("s_waitcnt vmcnt(0)");
    __syncthreads();
    int cur = 0;

    for (int kv0 = 0; kv0 < SSEQ; kv0 += 128) {
        if (kv0 + 128 < SSEQ) { STAGE(cur ^ 1, kv0 + 128) }

        // ---- S^T = K @ Q^T : s_kt holds S[q=l31][kv = crow(r,hi) + 32*kt]
        f32x16 s0 = {}, s1 = {}, s2 = {}, s3 = {};
        __builtin_amdgcn_s_setprio(1);
        #pragma unroll
        for (int st = 0; st < 4; st++) {
            int colb = st*16 + hi*8;
            int sw0 = colb ^ ((l31 & 7) << 3);
            short8 kf0 = *(const short8*)&Ks[cur][0][l31*64        + sw0];
            short8 kf1 = *(const short8*)&Ks[cur][0][(32 + l31)*64 + sw0];
            short8 kf2 = *(const short8*)&Ks[cur][1][l31*64        + sw0];
            short8 kf3 = *(const short8*)&Ks[cur][1][(32 + l31)*64 + sw0];
            s0 = MFMA32(kf0, qf[st], s0);
            s1 = MFMA32(kf1, qf[st], s1);
            s2 = MFMA32(kf2, qf[st], s2);
            s3 = MFMA32(kf3, qf[st], s3);
        }
        __builtin_amdgcn_s_setprio(0);

        // ---- online softmax (log2 domain), per-lane rows; 4-chain tree max over 64 vals
        float ma = fmaxf(s0[0], s0[1]);
        float mb = fmaxf(s0[2], s0[3]);
        float mc = fmaxf(s0[4], s0[5]);
        float md = fmaxf(s0[6], s0[7]);
        ma = fmaxf(fmaxf(ma, s0[8]),  s0[9]);
        mb = fmaxf(fmaxf(mb, s0[10]), s0[11]);
        mc = fmaxf(fmaxf(mc, s0[12]), s0[13]);
        md = fmaxf(fmaxf(md, s0[14]), s0[15]);
        ma = fmaxf(fmaxf(ma, s1[0]),  s1[1]);
        mb = fmaxf(fmaxf(mb, s1[2]),  s1[3]);
        mc = fmaxf(fmaxf(mc, s1[4]),  s1[5]);
        md = fmaxf(fmaxf(md, s1[6]),  s1[7]);
        ma = fmaxf(fmaxf(ma, s1[8]),  s1[9]);
        mb = fmaxf(fmaxf(mb, s1[10]), s1[11]);
        mc = fmaxf(fmaxf(mc, s1[12]), s1[13]);
        md = fmaxf(fmaxf(md, s1[14]), s1[15]);
        ma = fmaxf(fmaxf(ma, s2[0]),  s2[1]);
        mb = fmaxf(fmaxf(mb, s2[2]),  s2[3]);
        mc = fmaxf(fmaxf(mc, s2[4]),  s2[5]);
        md = fmaxf(fmaxf(md, s2[6]),  s2[7]);
        ma = fmaxf(fmaxf(ma, s2[8]),  s2[9]);
        mb = fmaxf(fmaxf(mb, s2[10]), s2[11]);
        mc = fmaxf(fmaxf(mc, s2[12]), s2[13]);
        md = fmaxf(fmaxf(md, s2[14]), s2[15]);
        ma = fmaxf(fmaxf(ma, s3[0]),  s3[1]);
        mb = fmaxf(fmaxf(mb, s3[2]),  s3[3]);
        mc = fmaxf(fmaxf(mc, s3[4]),  s3[5]);
        md = fmaxf(fmaxf(md, s3[6]),  s3[7]);
        ma = fmaxf(fmaxf(ma, s3[8]),  s3[9]);
        mb = fmaxf(fmaxf(mb, s3[10]), s3[11]);
        mc = fmaxf(fmaxf(mc, s3[12]), s3[13]);
        md = fmaxf(fmaxf(md, s3[14]), s3[15]);
        float mx = fmaxf(fmaxf(ma, mb), fmaxf(mc, md));
        mx = fmaxf(mx, __shfl_xor(mx, 32));

        if (__any(mx > m_run + 8.f)) {       // defer-max (T13)
            float mnew = fmaxf(m_run, mx);
            float alpha = __builtin_amdgcn_exp2f(m_run - mnew);
            #pragma unroll
            for (int r = 0; r < 16; r++) { o0[r] *= alpha; o1[r] *= alpha; }
            l_run *= alpha;
            m_run = mnew;
        }
        float r0 = 0.f, r1 = 0.f, r2 = 0.f, r3 = 0.f;
        #pragma unroll
        for (int r = 0; r < 16; r += 4) {
            s0[r]   = __builtin_amdgcn_exp2f(s0[r]   - m_run); r0 += s0[r];
            s0[r+1] = __builtin_amdgcn_exp2f(s0[r+1] - m_run); r1 += s0[r+1];
            s0[r+2] = __builtin_amdgcn_exp2f(s0[r+2] - m_run); r2 += s0[r+2];
            s0[r+3] = __builtin_amdgcn_exp2f(s0[r+3] - m_run); r3 += s0[r+3];
        }
        #pragma unroll
        for (int r = 0; r < 16; r += 4) {
            s1[r]   = __builtin_amdgcn_exp2f(s1[r]   - m_run); r0 += s1[r];
            s1[r+1] = __builtin_amdgcn_exp2f(s1[r+1] - m_run); r1 += s1[r+1];
            s1[r+2] = __builtin_amdgcn_exp2f(s1[r+2] - m_run); r2 += s1[r+2];
            s1[r+3] = __builtin_amdgcn_exp2f(s1[r+3] - m_run); r3 += s1[r+3];
        }
        #pragma unroll
        for (int r = 0; r < 16; r += 4) {
            s2[r]   = __builtin_amdgcn_exp2f(s2[r]   - m_run); r0 += s2[r];
            s2[r+1] = __builtin_amdgcn_exp2f(s2[r+1] - m_run); r1 += s2[r+1];
            s2[r+2] = __builtin_amdgcn_exp2f(s2[r+2] - m_run); r2 += s2[r+2];
            s2[r+3] = __builtin_amdgcn_exp2f(s2[r+3] - m_run); r3 += s2[r+3];
        }
        #pragma unroll
        for (int r = 0; r < 16; r += 4) {
            s3[r]   = __builtin_amdgcn_exp2f(s3[r]   - m_run); r0 += s3[r];
            s3[r+1] = __builtin_amdgcn_exp2f(s3[r+1] - m_run); r1 += s3[r+1];
            s3[r+2] = __builtin_amdgcn_exp2f(s3[r+2] - m_run); r2 += s3[r+2];
            s3[r+3] = __builtin_amdgcn_exp2f(s3[r+3] - m_run); r3 += s3[r+3];
        }
        float rs = (r0 + r1) + (r2 + r3);
        rs += __shfl_xor(rs, 32);
        l_run += rs;

        // ---- P -> bf16 B-fragments via v_cvt_pk_bf16_f32 + permlane32_swap (T12)
        // pfr[ks][j] = P[q=l31][kv = 16*ks + 8*hi + j], ks = 2*acc + sub
        short8 pfr[8];
        #define PACK8(SV, KS0) { \
            unsigned a0 = cvt_pk_bf16(SV[0], SV[1]); \
            unsigned a1 = cvt_pk_bf16(SV[2], SV[3]); \
            unsigned b0 = cvt_pk_bf16(SV[4], SV[5]); \
            unsigned b1 = cvt_pk_bf16(SV[6], SV[7]); \
            uint2v rr0 = __builtin_amdgcn_permlane32_swap(a0, b0, false, false); \
            uint2v rr1 = __builtin_amdgcn_permlane32_swap(a1, b1, false, false); \
            union { unsigned u[4]; short8 v; } pfa; \
            pfa.u[0] = rr0.x; pfa.u[1] = rr1.x; pfa.u[2] = rr0.y; pfa.u[3] = rr1.y; \
            pfr[KS0] = pfa.v; \
            unsigned c0 = cvt_pk_bf16(SV[8], SV[9]); \
            unsigned c1 = cvt_pk_bf16(SV[10], SV[11]); \
            unsigned d0 = cvt_pk_bf16(SV[12], SV[13]); \
            unsigned d1 = cvt_pk_bf16(SV[14], SV[15]); \
            uint2v rr2 = __builtin_amdgcn_permlane32_swap(c0, d0, false, false); \
            uint2v rr3 = __builtin_amdgcn_permlane32_swap(c1, d1, false, false); \
            union { unsigned u[4]; short8 v; } pfb; \
            pfb.u[0] = rr2.x; pfb.u[1] = rr3.x; pfb.u[2] = rr2.y; pfb.u[3] = rr3.y; \
            pfr[(KS0)+1] = pfb.v; \
        }
        PACK8(s0, 0)
        PACK8(s1, 2)
        PACK8(s2, 4)
        PACK8(s3, 6)
        #undef PACK8

        // ---- O^T += V^T P^T : lane holds O[q=l31][d=crow(r,hi)+32*dt]
        __builtin_amdgcn_s_setprio(1);
        #pragma unroll
        for (int ks = 0; ks < 8; ks++) {
            int sub = ks >> 2;
            int colb = (ks & 3)*16 + hi*8;
            int sw = colb ^ ((l31 & 7) << 3);
            short8 vf0 = *(const short8*)&Vs[cur][sub][l31*64        + sw];
            short8 vf1 = *(const short8*)&Vs[cur][sub][(32 + l31)*64 + sw];
            o0 = MFMA32(vf0, pfr[ks], o0);
            o1 = MFMA32(vf1, pfr[ks], o1);
        }
        __builtin_amdgcn_s_setprio(0);

        asm volatile("s_waitcnt vmcnt(0)");
        __syncthreads();
        cur ^= 1;
    }

    // ---- epilogue: normalize, LDS roundtrip for coalesced stores (8 x 4KB = all of Ks)
    float rl = 1.f / l_run;
    ushort_t* Ot = ((ushort_t*)Ks) + w*(32*64);
    #pragma unroll
    for (int dt = 0; dt < 2; dt++)
        #pragma unroll
        for (int rq = 0; rq < 4; rq++) {
            float v0 = (dt ? o1[rq*4+0] : o0[rq*4+0]) * rl;
            float v1 = (dt ? o1[rq*4+1] : o0[rq*4+1]) * rl;
            float v2 = (dt ? o1[rq*4+2] : o0[rq*4+2]) * rl;
            float v3 = (dt ? o1[rq*4+3] : o0[rq*4+3]) * rl;
            int d0 = dt*32 + rq*8 + hi*4;
            uint2v pw = { cvt_pk_bf16(v0, v1), cvt_pk_bf16(v2, v3) };
            *(uint2v*)&Ot[l31*64 + (d0 ^ ((l31 & 7) << 3))] = pw;
        }

    int b = bh >> 4, h = bh & 15;
    int q2 = l >> 1, dh = (l & 1) * 32;
    size_t obase = ((size_t)(b*SSEQ) + q0 + w*32 + q2)*EMBED + h*HDIM;
    #pragma unroll
    for (int j = 0; j < 4; j++) {
        int d = dh + j*8;
        short8 ov = *(short8*)&Ot[q2*64 + (d ^ ((q2 & 7) << 3))];
        *(short8*)&o[obase + d] = ov;
    }
}

extern "C" void kernel_launch(void* const* d_in, const int* in_sizes, int n_in,
                              void* d_out, int out_size, void* d_ws, size_t ws_size,
                              hipStream_t stream) {
    const float* x  = (const float*)d_in[0];
    const float* Wq = (const float*)d_in[1];
    const float* bq = (const float*)d_in[2];
    const float* Wk = (const float*)d_in[3];
    const float* bk = (const float*)d_in[4];
    const float* Wv = (const float*)d_in[5];
    const float* bv = (const float*)d_in[6];
    const float* Wo = (const float*)d_in[7];
    const float* bo = (const float*)d_in[8];

    char* ws = (char*)d_ws;
    ushort_t* xb  = (ushort_t*)(ws);                    // 0-8 MB: x bf16, later reused as attn-out
    ushort_t* WqT = (ushort_t*)(ws + (8u  << 20));      // WqT|WkT|WvT contiguous [3072][1024]
    ushort_t* WkT = (ushort_t*)(ws + (10u << 20));
    ushort_t* WvT = (ushort_t*)(ws + (12u << 20));
    ushort_t* WoT = (ushort_t*)(ws + (14u << 20));
    ushort_t* qb  = (ushort_t*)(ws + (16u << 20));      // q|k contiguous, 8 MB each
    ushort_t* kb  = (ushort_t*)(ws + (24u << 20));
    ushort_t* vtb = (ushort_t*)(ws + (40u << 20));      // V transposed [B,H,D,S] (written by GEMM)
    ushort_t* ab  = xb;

    prep_kernel<<<dim3(32, 32, 5), dim3(32, 8), 0, stream>>>(
        x, xb, Wq, Wk, Wv, Wo, WqT, WkT, WvT, WoT);

    gemm_bt_kernel<2><<<dim3(QKV_N/128, MROWS/128), 256, 0, stream>>>(
        xb, WqT, bq, bk, bv, qb, vtb, MROWS, QKV_N, EMBED);

    flash_attn2_kernel<<<256, 512, 0, stream>>>(qb, kb, vtb, ab);

    gemm_bt_kernel<0><<<dim3(EMBED/128, MROWS/128), 256, 0, stream>>>(
        ab, WoT, bo, bo, bo, d_out, nullptr, MROWS, EMBED, EMBED);
}